// Round 15
// baseline (238.045 us; speedup 1.0000x reference)
//
#include <hip/hip_runtime.h>
#include <cstdint>

#define EPSF 1e-15f
#define MAXN (1.0f - 1e-5f)
#define BSH 9   // 512 slots per bin

typedef __attribute__((ext_vector_type(8))) short bf16x8;
typedef __attribute__((ext_vector_type(4))) float f32x4;
typedef unsigned short ushort_t;

__device__ __forceinline__ float wsum64(float v) {
    v += __shfl_xor(v, 1);
    v += __shfl_xor(v, 2);
    v += __shfl_xor(v, 4);
    v += __shfl_xor(v, 8);
    v += __shfl_xor(v, 16);
    v += __shfl_xor(v, 32);
    return v;
}

__device__ __forceinline__ float dot4(float4 a, float4 b) {
    return a.x * b.x + a.y * b.y + a.z * b.z + a.w * b.w;
}

__device__ __forceinline__ float frcp(float x) {
    return __builtin_amdgcn_rcpf(x);
}

__device__ __forceinline__ float tanh_f(float x) {
    x = fminf(x, 10.f);
    float t = __expf(2.f * x);
    return (t - 1.f) * frcp(t + 1.f);
}

__device__ __forceinline__ float atanh_f(float x) {
    return 0.5f * __logf((1.f + x) * frcp(1.f - x));
}

__device__ __forceinline__ ushort_t f2bf(float f) {
    uint32_t b = __float_as_uint(f);
    b = (b + 0x7FFF + ((b >> 16) & 1)) >> 16;
    return (ushort_t)b;
}

__device__ __forceinline__ float bf2f(ushort_t h) {
    return __uint_as_float((uint32_t)h << 16);
}

__device__ __forceinline__ bf16x8 pack8(const float* __restrict__ p) {
    float4 lo = *(const float4*)p;
    float4 hi = *(const float4*)(p + 4);
    bf16x8 r;
    r[0] = (short)f2bf(lo.x); r[1] = (short)f2bf(lo.y);
    r[2] = (short)f2bf(lo.z); r[3] = (short)f2bf(lo.w);
    r[4] = (short)f2bf(hi.x); r[5] = (short)f2bf(hi.y);
    r[6] = (short)f2bf(hi.z); r[7] = (short)f2bf(hi.w);
    return r;
}

// Convert ent/usr/rel to bf16 tables (entH, catH user section, relH).
__global__ __launch_bounds__(256) void cvt3_k(
        const float* __restrict__ ent, const float* __restrict__ usr,
        const float* __restrict__ rel,
        ushort_t* __restrict__ entH, ushort_t* __restrict__ usrH,
        ushort_t* __restrict__ relH, long nE, long nU, long nR) {
    long i = ((long)blockIdx.x * blockDim.x + threadIdx.x) * 8;
    const float* s; ushort_t* d; long off;
    if (i < nE) { s = ent; d = entH; off = i; }
    else if (i < nE + nU) { s = usr; d = usrH; off = i - nE; }
    else if (i < nE + nU + nR) { s = rel; d = relH; off = i - nE - nU; }
    else return;
    float4 a = *(const float4*)(s + off);
    float4 b = *(const float4*)(s + off + 4);
    ushort4 lo; lo.x = f2bf(a.x); lo.y = f2bf(a.y); lo.z = f2bf(a.z); lo.w = f2bf(a.w);
    ushort4 hi; hi.x = f2bf(b.x); hi.y = f2bf(b.y); hi.z = f2bf(b.z); hi.w = f2bf(b.w);
    *(ushort4*)(d + off) = lo;
    *(ushort4*)(d + off + 4) = hi;
}

// ---------------- CSR build: binned counting sort (zero global atomics) ------

// P1: per-block LDS histogram over coarse bins; write block's bin row.
__global__ __launch_bounds__(256) void p1_hist_k(
        const int* __restrict__ kg_src, const int* __restrict__ iu_dst,
        const int* __restrict__ ui_dst, int* __restrict__ H,
        int E_kg, int E_iu, int E_ui, int n_items, int S1, int SU, int nbins) {
    __shared__ int h[512];
    int tid = threadIdx.x;
    h[tid] = 0; h[tid + 256] = 0;
    __syncthreads();
    long tot = (long)E_kg + E_iu + E_ui;
    long b0 = (long)blockIdx.x * 2048 + tid;
#pragma unroll
    for (int j = 0; j < 8; ++j) {
        long t = b0 + (long)j * 256;
        if (t < tot) {
            int slot;
            if (t < E_kg) slot = kg_src[t];
            else if (t < (long)E_kg + E_iu) slot = S1 + iu_dst[t - E_kg] - n_items;
            else slot = S1 + SU + ui_dst[t - E_kg - E_iu];
            atomicAdd(&h[slot >> BSH], 1);
        }
    }
    __syncthreads();
    int* row = H + (size_t)blockIdx.x * nbins;
    if (tid < nbins) row[tid] = h[tid];
    if (tid + 256 < nbins) row[tid + 256] = h[tid + 256];
}

// P2a: per-bin column scan over blocks (in place) -> binTotal.
__global__ __launch_bounds__(256) void p2a_scan_k(int* __restrict__ H,
        int* __restrict__ binTotal, int NBLK, int nbins) {
    int bin = blockIdx.x, tid = threadIdx.x;
    int lane = tid & 63, w = tid >> 6;
    __shared__ int wtot[4];
    int carry = 0;
    for (int c0 = 0; c0 < NBLK; c0 += 256) {
        int idx = c0 + tid;
        int v = (idx < NBLK) ? H[(size_t)idx * nbins + bin] : 0;
        int inc = v;
#pragma unroll
        for (int off = 1; off < 64; off <<= 1) {
            int u = __shfl_up(inc, off);
            if (lane >= off) inc += u;
        }
        if (lane == 63) wtot[w] = inc;
        __syncthreads();
        int woff = 0;
        for (int i = 0; i < w; ++i) woff += wtot[i];
        int ctot = wtot[0] + wtot[1] + wtot[2] + wtot[3];
        if (idx < NBLK) H[(size_t)idx * nbins + bin] = carry + woff + inc - v;
        carry += ctot;
        __syncthreads();
    }
    if (tid == 0) binTotal[bin] = carry;
}

// P2b: exclusive scan of binTotal -> binStart (nbins <= 512).
__global__ __launch_bounds__(512) void p2b_bins_k(const int* __restrict__ binTotal,
        int* __restrict__ binStart, int nbins) {
    int tid = threadIdx.x, lane = tid & 63, w = tid >> 6;
    __shared__ int wtot[8];
    int v = (tid < nbins) ? binTotal[tid] : 0;
    int inc = v;
#pragma unroll
    for (int off = 1; off < 64; off <<= 1) {
        int u = __shfl_up(inc, off);
        if (lane >= off) inc += u;
    }
    if (lane == 63) wtot[w] = inc;
    __syncthreads();
    int woff = 0;
    for (int i = 0; i < w; ++i) woff += wtot[i];
    if (tid < nbins) binStart[tid] = woff + inc - v;
    if (tid == 0) {
        int tot = 0;
        for (int i = 0; i < 8; ++i) tot += wtot[i];
        binStart[nbins] = tot;
    }
}

// P3: scatter records into bin-grouped order via LDS cursors.
__global__ __launch_bounds__(256) void p3_scat_k(
        const int* __restrict__ kg_src, const int* __restrict__ kg_dst,
        const int* __restrict__ kg_typ, const int* __restrict__ iu_src,
        const int* __restrict__ iu_dst, const int* __restrict__ ui_src,
        const int* __restrict__ ui_dst,
        const int* __restrict__ H, const int* __restrict__ binStart,
        int2* __restrict__ recA,
        int E_kg, int E_iu, int E_ui, int n_items, int S1, int SU, int nbins) {
    __shared__ int off[512];
    int tid = threadIdx.x;
    const int* row = H + (size_t)blockIdx.x * nbins;
    if (tid < nbins) off[tid] = binStart[tid] + row[tid];
    if (tid + 256 < nbins) off[tid + 256] = binStart[tid + 256] + row[tid + 256];
    __syncthreads();
    long tot = (long)E_kg + E_iu + E_ui;
    long b0 = (long)blockIdx.x * 2048 + tid;
#pragma unroll
    for (int j = 0; j < 8; ++j) {
        long t = b0 + (long)j * 256;
        if (t < tot) {
            int slot, aux;
            if (t < E_kg) {
                slot = kg_src[t];
                aux = kg_dst[t] | ((kg_typ[t] + 2) << 18);
            } else if (t < (long)E_kg + E_iu) {
                long e = t - E_kg;
                slot = S1 + iu_dst[e] - n_items;
                aux = iu_src[e];
            } else {
                long e = t - E_kg - E_iu;
                slot = S1 + SU + ui_dst[e];
                aux = ui_src[e];
            }
            int pos = atomicAdd(&off[slot >> BSH], 1);
            recA[pos] = make_int2(slot, aux);
        }
    }
}

// P4: per-bin fine sort: LDS hist over 512 slots -> deg/base + final scatter.
__global__ __launch_bounds__(256) void p4_sort_k(
        const int2* __restrict__ recA, const int* __restrict__ binStart,
        int2* __restrict__ recB, int* __restrict__ deg, int* __restrict__ base,
        int nbins) {
    int b = blockIdx.x, tid = threadIdx.x;
    int lane = tid & 63, w = tid >> 6;
    int lo = binStart[b], cnt = binStart[b + 1] - lo;
    __shared__ int h[512];
    __shared__ int pre[512];
    __shared__ int wtot[4];
    h[tid] = 0; h[tid + 256] = 0;
    __syncthreads();
    for (int i = tid; i < cnt; i += 256)
        atomicAdd(&h[recA[lo + i].x & 511], 1);
    __syncthreads();
    int v1 = h[tid];
    int inc = v1;
#pragma unroll
    for (int off = 1; off < 64; off <<= 1) {
        int u = __shfl_up(inc, off);
        if (lane >= off) inc += u;
    }
    if (lane == 63) wtot[w] = inc;
    __syncthreads();
    int woff = 0;
    for (int i = 0; i < w; ++i) woff += wtot[i];
    int T1 = wtot[0] + wtot[1] + wtot[2] + wtot[3];
    int p1 = woff + inc - v1;
    __syncthreads();
    int v2 = h[tid + 256];
    inc = v2;
#pragma unroll
    for (int off = 1; off < 64; off <<= 1) {
        int u = __shfl_up(inc, off);
        if (lane >= off) inc += u;
    }
    if (lane == 63) wtot[w] = inc;
    __syncthreads();
    woff = 0;
    for (int i = 0; i < w; ++i) woff += wtot[i];
    int p2 = T1 + woff + inc - v2;
    pre[tid] = p1; pre[tid + 256] = p2;
    int slot0 = (b << BSH) + tid;
    deg[slot0] = v1;       base[slot0] = lo + p1;
    deg[slot0 + 256] = v2; base[slot0 + 256] = lo + p2;
    __syncthreads();
    for (int i = tid; i < cnt; i += 256) {
        int2 r = recA[lo + i];
        int p = atomicAdd(&pre[r.x & 511], 1);
        recB[lo + p] = r;
    }
}

// ---------------- KG path ----------------

// Merged dots+chain in CSR (slot) order; 4 lanes/edge coalesced reads,
// 2-step shfl reduce, fast-math chain; payload write coalesced at slot.
__global__ __launch_bounds__(256) void kg_edge_fused_k(const float* __restrict__ ent,
                          const float* __restrict__ rel,
                          const int2* __restrict__ rec,
                          float4* __restrict__ payload,
                          int nE) {
    int w = blockIdx.x * 4 + (threadIdx.x >> 6);
    int l = threadIdx.x & 63;
    int slot = w * 16 + (l >> 2);
    if (slot >= nE) return;
    int j0 = l & 3;
    int2 rc = rec[slot];
    int s = rc.x, d = rc.y & 0x3FFFF, ty = rc.y >> 18;
    const float4* pu = (const float4*)(ent + (size_t)s * 64);
    const float4* pv = (const float4*)(ent + (size_t)d * 64);
    const float4* pr = (const float4*)(rel + (size_t)ty * 64);

    float uu = 0.f, vv = 0.f, rr = 0.f, uv = 0.f, ur = 0.f, vr = 0.f;
#pragma unroll
    for (int i = 0; i < 4; ++i) {
        float4 a = pu[4 * i + j0], b = pv[4 * i + j0], c = pr[4 * i + j0];
        uu += dot4(a, a); vv += dot4(b, b); rr += dot4(c, c);
        uv += dot4(a, b); ur += dot4(a, c); vr += dot4(b, c);
    }
#pragma unroll
    for (int m = 1; m < 4; m <<= 1) {
        uu += __shfl_xor(uu, m);
        vv += __shfl_xor(vv, m);
        rr += __shfl_xor(rr, m);
        uv += __shfl_xor(uv, m);
        ur += __shfl_xor(ur, m);
        vr += __shfl_xor(vr, m);
    }

    float n0 = sqrtf(fmaxf(uu, EPSF));
    float cp = tanh_f(n0) * frcp(n0);
    float p2 = cp * cp * uu;
    float om_p2 = 1.f - p2;
    float lam = 2.f * frcp(fmaxf(om_p2, EPSF));

    float nv = sqrtf(fmaxf(vv, EPSF));
    float cd = tanh_f(0.5f * lam * nv) * frcp(nv);
    float wd2 = cd * cd * vv;
    float pwd = cp * cd * uv;
    float iDd = frcp(fmaxf(1.f + 2.f * pwd + p2 * wd2, EPSF));
    float a1 = (1.f + 2.f * pwd + wd2) * cp * iDd;
    float b1 = om_p2 * cd * iDd;

    float nr = sqrtf(fmaxf(rr, EPSF));
    float cr = tanh_f(0.5f * lam * nr) * frcp(nr);
    float wr2 = cr * cr * rr;
    float pwr = cp * cr * ur;
    float iDr = frcp(fmaxf(1.f + 2.f * pwr + p2 * wr2, EPSF));
    float a2 = (1.f + 2.f * pwr + wr2) * cp * iDr;
    float c2 = om_p2 * cr * iDr;

    float x2 = a1 * a1 * uu + 2.f * a1 * b1 * uv + b1 * b1 * vv;
    float y2 = a2 * a2 * uu + 2.f * a2 * c2 * ur + c2 * c2 * rr;
    float xy = a1 * a2 * uu + a1 * c2 * ur + b1 * a2 * uv + b1 * c2 * vr;
    float iden = frcp(fmaxf(1.f + 2.f * xy + x2 * y2, EPSF));
    float E = (1.f + 2.f * xy + y2) * iden;
    float F = (1.f - x2) * iden;
    float zu = E * a1 + F * a2;
    float zv = E * b1;
    float zr = F * c2;

    float z2 = zu * zu * uu + zv * zv * vv + zr * zr * rr
             + 2.f * (zu * zv * uv + zu * zr * ur + zv * zr * vr);
    float nz = sqrtf(fmaxf(z2, EPSF));
    if (nz > MAXN) {
        float sc = MAXN * frcp(nz);
        zu *= sc; zv *= sc; zr *= sc;
        z2 *= sc * sc;
    }

    float mxy = -cp * (zu * uu + zv * uv + zr * ur);
    float idenl = frcp(fmaxf(1.f + 2.f * mxy + p2 * z2, EPSF));
    float G = (1.f + 2.f * mxy + z2) * idenl;
    float H = om_p2 * idenl;
    float su = -G * cp + H * zu;
    float sv = H * zv;
    float sr = H * zr;

    float ns2 = su * su * uu + sv * sv * vv + sr * sr * rr
              + 2.f * (su * sv * uv + su * sr * ur + sv * sr * vr);
    float ns = sqrtf(fmaxf(ns2, EPSF));
    float k = fmaxf(om_p2, EPSF) * atanh_f(fminf(ns, MAXN)) * frcp(ns);

    if (j0 == 0) {
        payload[slot] = make_float4(k * sv, k * sr, k * su, __int_as_float(rc.y));
    }
}

// Wave = 2 consecutive entities, combined contiguous slot range, 8-deep
// unroll; v/r rows from bf16 tables (half the random-gather bytes).
// Also emits item-row norms and the bf16 catH item rows.
__global__ void kg_gather_k(const float* __restrict__ ent,
                            const ushort_t* __restrict__ entH,
                            const ushort_t* __restrict__ relH,
                            const int* __restrict__ deg,
                            const int* __restrict__ base,
                            const float4* __restrict__ payload,
                            float* __restrict__ out_final,
                            float* __restrict__ out_items,
                            ushort_t* __restrict__ catH,
                            float* __restrict__ normv,
                            int n_items, int n) {
    int w = blockIdx.x * (blockDim.x >> 6) + (threadIdx.x >> 6);
    int i0 = w * 2;
    if (i0 >= n) return;
    bool has1 = (i0 + 1 < n);
    int l = threadIdx.x & 63;
    int b0 = base[i0];
    int d0 = deg[i0];
    int d1 = has1 ? deg[i0 + 1] : 0;
    int cnt = d0 + d1;
    int split = b0 + d0;
    float acc0 = 0.f, as0 = 0.f, acc1 = 0.f, as1 = 0.f;
    int q = 0;
    for (; q + 8 <= cnt; q += 8) {
        float4 p[8]; float vv[8], rr_[8];
#pragma unroll
        for (int j = 0; j < 8; ++j) p[j] = payload[b0 + q + j];
#pragma unroll
        for (int j = 0; j < 8; ++j) {
            int wd = __float_as_int(p[j].w);
            vv[j] = bf2f(entH[(size_t)(wd & 0x3FFFF) * 64 + l]);
            rr_[j] = bf2f(relH[(size_t)(wd >> 18) * 64 + l]);
        }
#pragma unroll
        for (int j = 0; j < 8; ++j) {
            float t = p[j].x * vv[j] + p[j].y * rr_[j];
            bool s0 = (b0 + q + j) < split;
            acc0 += s0 ? t : 0.f;
            acc1 += s0 ? 0.f : t;
            as0 += s0 ? p[j].z : 0.f;
            as1 += s0 ? 0.f : p[j].z;
        }
    }
    for (; q < cnt; ++q) {
        float4 p = payload[b0 + q];
        int wd = __float_as_int(p.w);
        float t = p.x * bf2f(entH[(size_t)(wd & 0x3FFFF) * 64 + l])
                + p.y * bf2f(relH[(size_t)(wd >> 18) * 64 + l]);
        bool s0 = (b0 + q) < split;
        acc0 += s0 ? t : 0.f;
        acc1 += s0 ? 0.f : t;
        as0 += s0 ? p.z : 0.f;
        as1 += s0 ? 0.f : p.z;
    }
    {
        float v = (acc0 + as0 * ent[(size_t)i0 * 64 + l]) * frcp(fmaxf((float)d0, 1.f));
        if (i0 < n_items) {
            out_items[(size_t)i0 * 64 + l] = v;
            catH[(size_t)i0 * 64 + l] = f2bf(v);
            float s2 = wsum64(v * v);
            if (l == 0) normv[i0] = s2;
        } else {
            out_final[(size_t)i0 * 64 + l] = v;
        }
    }
    if (has1) {
        int i1 = i0 + 1;
        float v = (acc1 + as1 * ent[(size_t)i1 * 64 + l]) * frcp(fmaxf((float)d1, 1.f));
        if (i1 < n_items) {
            out_items[(size_t)i1 * 64 + l] = v;
            catH[(size_t)i1 * 64 + l] = f2bf(v);
            float s2 = wsum64(v * v);
            if (l == 0) normv[i1] = s2;
        } else {
            out_final[(size_t)i1 * 64 + l] = v;
        }
    }
}

// norms for the user half of cat_nodes
__global__ void user_norm_k(const float* __restrict__ user, float* __restrict__ normv,
                            int n_items, int n_usr) {
    int j = blockIdx.x * (blockDim.x >> 6) + (threadIdx.x >> 6);
    if (j >= n_usr) return;
    int l = threadIdx.x & 63;
    float c = user[(size_t)j * 64 + l];
    float s = wsum64(c * c);
    if (l == 0) normv[n_items + j] = s;
}

// ---------------- CF path ----------------

// Wave = 2 consecutive users, combined contiguous range, 8-deep unroll,
// unified bf16 cat table (no items/user branch).
__global__ void iu_gather_k(const ushort_t* __restrict__ catH,
                            const int* __restrict__ deg, const int* __restrict__ base,
                            const int2* __restrict__ rec,
                            float* __restrict__ out_u, int n, int SOFF) {
    int w = blockIdx.x * (blockDim.x >> 6) + (threadIdx.x >> 6);
    int i0 = w * 2;
    if (i0 >= n) return;
    bool has1 = (i0 + 1 < n);
    int l = threadIdx.x & 63;
    int b0 = base[SOFF + i0];
    int d0 = deg[SOFF + i0];
    int d1 = has1 ? deg[SOFF + i0 + 1] : 0;
    int cnt = d0 + d1;
    int split = b0 + d0;
    float acc0 = 0.f, acc1 = 0.f;
    int q = 0;
    for (; q + 8 <= cnt; q += 8) {
        float vs[8]; bool s0[8];
#pragma unroll
        for (int j = 0; j < 8; ++j) {
            int sidx = rec[b0 + q + j].y;
            vs[j] = bf2f(catH[(size_t)sidx * 64 + l]);
            s0[j] = (b0 + q + j) < split;
        }
#pragma unroll
        for (int j = 0; j < 8; ++j) {
            acc0 += s0[j] ? vs[j] : 0.f;
            acc1 += s0[j] ? 0.f : vs[j];
        }
    }
    for (; q < cnt; ++q) {
        int sidx = rec[b0 + q].y;
        float v = bf2f(catH[(size_t)sidx * 64 + l]);
        bool s0 = (b0 + q) < split;
        acc0 += s0 ? v : 0.f;
        acc1 += s0 ? 0.f : v;
    }
    out_u[(size_t)i0 * 64 + l] = acc0 * frcp(fmaxf((float)d0, 1.f));
    if (has1)
        out_u[(size_t)(i0 + 1) * 64 + l] = acc1 * frcp(fmaxf((float)d1, 1.f));
}

// Wave = 2 consecutive items, combined range, 8-deep unroll:
// icf[i] = norm[i]*(sum cat[s]/(norm[s]+1e-6))/deg, bf16 cat rows.
__global__ void ui_gather_k(const ushort_t* __restrict__ catH,
                            const float* __restrict__ normv,
                            const int* __restrict__ deg, const int* __restrict__ base,
                            const int2* __restrict__ rec,
                            float* __restrict__ icf, int n, int SOFF) {
    int w = blockIdx.x * (blockDim.x >> 6) + (threadIdx.x >> 6);
    int i0 = w * 2;
    if (i0 >= n) return;
    bool has1 = (i0 + 1 < n);
    int l = threadIdx.x & 63;
    int b0 = base[SOFF + i0];
    int d0 = deg[SOFF + i0];
    int d1 = has1 ? deg[SOFF + i0 + 1] : 0;
    int cnt = d0 + d1;
    int split = b0 + d0;
    float acc0 = 0.f, acc1 = 0.f;
    int q = 0;
    for (; q + 8 <= cnt; q += 8) {
        int ss[8]; float fs[8], vs[8]; bool s0[8];
#pragma unroll
        for (int j = 0; j < 8; ++j) ss[j] = rec[b0 + q + j].y;
#pragma unroll
        for (int j = 0; j < 8; ++j) fs[j] = frcp(normv[ss[j]] + 1e-6f);
#pragma unroll
        for (int j = 0; j < 8; ++j) {
            vs[j] = bf2f(catH[(size_t)ss[j] * 64 + l]);
            s0[j] = (b0 + q + j) < split;
        }
#pragma unroll
        for (int j = 0; j < 8; ++j) {
            float t = fs[j] * vs[j];
            acc0 += s0[j] ? t : 0.f;
            acc1 += s0[j] ? 0.f : t;
        }
    }
    for (; q < cnt; ++q) {
        int sidx = rec[b0 + q].y;
        float t = frcp(normv[sidx] + 1e-6f) * bf2f(catH[(size_t)sidx * 64 + l]);
        bool s0 = (b0 + q) < split;
        acc0 += s0 ? t : 0.f;
        acc1 += s0 ? 0.f : t;
    }
    icf[(size_t)i0 * 64 + l] = normv[i0] * acc0 * frcp(fmaxf((float)d0, 1.f));
    if (has1)
        icf[(size_t)(i0 + 1) * 64 + l] =
            normv[i0 + 1] * acc1 * frcp(fmaxf((float)d1, 1.f));
}

// MFMA gate+fusion: acc = [oi|cf] @ [W1;W2]^T (bf16), out = g*oi + (1-g)*cf.
__global__ __launch_bounds__(256) void fusion_mfma_k(const float* __restrict__ items,
                          const float* __restrict__ icf,
                          const float* __restrict__ W1, const float* __restrict__ W2,
                          float* __restrict__ outf, int n_items) {
    int lane = threadIdx.x & 63;
    int row0 = blockIdx.x * 64 + (threadIdx.x >> 6) * 16;
    int r = lane & 15, g = lane >> 4;

    int arow = row0 + r;
    size_t rbase = (size_t)(arow < n_items ? arow : 0) * 64;

    bf16x8 afrag[4];
#pragma unroll
    for (int s = 0; s < 4; ++s) {
        int kb = s * 32 + g * 8;
        const float* p = (kb < 64) ? (items + rbase + kb) : (icf + rbase + kb - 64);
        afrag[s] = pack8(p);
    }

    bf16x8 bfrag[4][4];
#pragma unroll
    for (int c = 0; c < 4; ++c) {
        int col = c * 16 + r;
#pragma unroll
        for (int s = 0; s < 4; ++s) {
            int kb = s * 32 + g * 8;
            const float* p = (kb < 64) ? (W1 + col * 64 + kb) : (W2 + col * 64 + kb - 64);
            bfrag[c][s] = pack8(p);
        }
    }

    f32x4 acc[4] = {{0.f,0.f,0.f,0.f},{0.f,0.f,0.f,0.f},
                    {0.f,0.f,0.f,0.f},{0.f,0.f,0.f,0.f}};
#pragma unroll
    for (int s = 0; s < 4; ++s)
#pragma unroll
        for (int c = 0; c < 4; ++c)
            acc[c] = __builtin_amdgcn_mfma_f32_16x16x32_bf16(afrag[s], bfrag[c][s],
                                                             acc[c], 0, 0, 0);

#pragma unroll
    for (int c = 0; c < 4; ++c) {
        int col = c * 16 + r;
#pragma unroll
        for (int q = 0; q < 4; ++q) {
            int orow = row0 + g * 4 + q;
            if (orow < n_items) {
                size_t off = (size_t)orow * 64 + col;
                float oi = items[off], cf = icf[off];
                float gate = frcp(1.f + __expf(-acc[c][q]));
                outf[off] = gate * oi + (1.f - gate) * cf;
            }
        }
    }
}

extern "C" void kernel_launch(void* const* d_in, const int* in_sizes, int n_in,
                              void* d_out, int out_size, void* d_ws, size_t ws_size,
                              hipStream_t stream) {
    const float* ent    = (const float*)d_in[0];
    const float* usr    = (const float*)d_in[1];
    const float* rel    = (const float*)d_in[2];
    const float* W1     = (const float*)d_in[3];
    const float* W2     = (const float*)d_in[4];
    const int*   kg_src = (const int*)d_in[5];
    const int*   kg_dst = (const int*)d_in[6];
    const int*   kg_typ = (const int*)d_in[7];
    const int*   iu_src = (const int*)d_in[8];
    const int*   iu_dst = (const int*)d_in[9];
    const int*   ui_src = (const int*)d_in[10];
    const int*   ui_dst = (const int*)d_in[11];

    const int n_ent   = in_sizes[0] / 64;
    const int n_usr   = in_sizes[1] / 64;
    const int n_rel   = in_sizes[2] / 64;
    const int E_kg    = in_sizes[5];
    const int E_iu    = in_sizes[8];
    const int E_ui    = in_sizes[10];
    const int n_items = (out_size - in_sizes[0] - in_sizes[1]) / 64;
    const int N       = n_items + n_usr;

    // unified slot space: [ent | user | item], each 512-aligned
    const int S1 = ((n_ent + 511) / 512) * 512;
    const int SU = ((n_usr + 511) / 512) * 512;
    const int SI = ((n_items + 511) / 512) * 512;
    const int S3 = S1 + SU + SI;
    const int nbins = S3 >> BSH;
    const long tot = (long)E_kg + E_iu + E_ui;
    const int NBLK = (int)((tot + 2047) / 2048);

    float* out_final = (float*)d_out;                        // (n_ent,64)
    float* out_u     = out_final + (size_t)n_ent * 64;       // (n_usr,64)
    float* out_items = out_u + (size_t)n_usr * 64;           // (n_items,64)

    // d_out tail scratch (dead before kg/iu gathers write these chunks):
    int2* recA = (int2*)out_u;                               // tot * 8B
    int*  H    = (int*)(recA + tot);                         // NBLK*nbins*4B

    float* ws = (float*)d_ws;
    size_t o = 0;
    int* binTotal = (int*)(ws + o); o += nbins;
    int* binStart = (int*)(ws + o); o += nbins + 1;
    int* deg      = (int*)(ws + o); o += S3;
    int* basep    = (int*)(ws + o); o += S3;
    o = (o + 3) & ~(size_t)3;                      // 16B align
    int2* recB    = (int2*)(ws + o); o += (size_t)tot * 2;
    float4* pay_kg = (float4*)(ws + o); o += (size_t)E_kg * 4;
    float* icf    = (float*)pay_kg;   // alias: pay_kg dead after kg_gather
    float* normv  = ws + o; o += N;
    o = (o + 3) & ~(size_t)3;
    ushort_t* entH = (ushort_t*)(ws + o); o += (size_t)n_ent * 32;
    ushort_t* catH = (ushort_t*)(ws + o); o += (size_t)N * 32;
    ushort_t* relH = (ushort_t*)(ws + o); o += (size_t)n_rel * 32;
    ushort_t* usrH = catH + (size_t)n_items * 64;  // user section of catH

    // bf16 tables (runs first; no deps on sort)
    long nE64 = (long)n_ent * 64, nU64 = (long)n_usr * 64, nR64 = (long)n_rel * 64;
    long tcvt = (nE64 + nU64 + nR64) / 8;
    cvt3_k<<<(int)((tcvt + 255) / 256), 256, 0, stream>>>(ent, usr, rel,
                                                          entH, usrH, relH,
                                                          nE64, nU64, nR64);

    // CSR build (all LDS atomics; no memsets - every buffer fully written)
    p1_hist_k<<<NBLK, 256, 0, stream>>>(kg_src, iu_dst, ui_dst, H,
                                        E_kg, E_iu, E_ui, n_items, S1, SU, nbins);
    p2a_scan_k<<<nbins, 256, 0, stream>>>(H, binTotal, NBLK, nbins);
    p2b_bins_k<<<1, 512, 0, stream>>>(binTotal, binStart, nbins);
    p3_scat_k<<<NBLK, 256, 0, stream>>>(kg_src, kg_dst, kg_typ, iu_src, iu_dst,
                                        ui_src, ui_dst, H, binStart, recA,
                                        E_kg, E_iu, E_ui, n_items, S1, SU, nbins);
    p4_sort_k<<<nbins, 256, 0, stream>>>(recA, binStart, recB, deg, basep, nbins);

    // KG compute (CSR-ordered edge pass; kg records = recB[0..E_kg))
    kg_edge_fused_k<<<(E_kg + 63) / 64, 256, 0, stream>>>(ent, rel, recB,
                                                          pay_kg, E_kg);
    int wv_e = (n_ent + 1) / 2;
    kg_gather_k<<<(wv_e + 3) / 4, 256, 0, stream>>>(ent, entH, relH, deg, basep,
                                                    pay_kg, out_final, out_items,
                                                    catH, normv, n_items, n_ent);
    user_norm_k<<<(n_usr + 3) / 4, 256, 0, stream>>>(usr, normv, n_items, n_usr);

    // CF gathers (direct output writes; recA/H in d_out are dead by now)
    int wv_u = (n_usr + 1) / 2;
    iu_gather_k<<<(wv_u + 3) / 4, 256, 0, stream>>>(catH, deg, basep, recB,
                                                    out_u, n_usr, S1);
    int wv_i = (n_items + 1) / 2;
    ui_gather_k<<<(wv_i + 3) / 4, 256, 0, stream>>>(catH, normv, deg, basep, recB,
                                                    icf, n_items, S1 + SU);
    fusion_mfma_k<<<(n_items + 63) / 64, 256, 0, stream>>>(out_items, icf, W1, W2,
                                                           out_final, n_items);
}

// Round 16
// 230.271 us; speedup vs baseline: 1.0338x; 1.0338x over previous
//
#include <hip/hip_runtime.h>
#include <cstdint>

#define EPSF 1e-15f
#define MAXN (1.0f - 1e-5f)
#define BSH 9   // 512 slots per bin

typedef __attribute__((ext_vector_type(8))) short bf16x8;
typedef __attribute__((ext_vector_type(4))) float f32x4;
typedef unsigned short ushort_t;

__device__ __forceinline__ float wsum64(float v) {
    v += __shfl_xor(v, 1);
    v += __shfl_xor(v, 2);
    v += __shfl_xor(v, 4);
    v += __shfl_xor(v, 8);
    v += __shfl_xor(v, 16);
    v += __shfl_xor(v, 32);
    return v;
}

__device__ __forceinline__ float dot4(float4 a, float4 b) {
    return a.x * b.x + a.y * b.y + a.z * b.z + a.w * b.w;
}

__device__ __forceinline__ float frcp(float x) {
    return __builtin_amdgcn_rcpf(x);
}

__device__ __forceinline__ float tanh_f(float x) {
    x = fminf(x, 10.f);
    float t = __expf(2.f * x);
    return (t - 1.f) * frcp(t + 1.f);
}

__device__ __forceinline__ float atanh_f(float x) {
    return 0.5f * __logf((1.f + x) * frcp(1.f - x));
}

__device__ __forceinline__ ushort_t f2bf(float f) {
    uint32_t b = __float_as_uint(f);
    b = (b + 0x7FFF + ((b >> 16) & 1)) >> 16;
    return (ushort_t)b;
}

__device__ __forceinline__ float bf2f(ushort_t h) {
    return __uint_as_float((uint32_t)h << 16);
}

__device__ __forceinline__ bf16x8 pack8(const float* __restrict__ p) {
    float4 lo = *(const float4*)p;
    float4 hi = *(const float4*)(p + 4);
    bf16x8 r;
    r[0] = (short)f2bf(lo.x); r[1] = (short)f2bf(lo.y);
    r[2] = (short)f2bf(lo.z); r[3] = (short)f2bf(lo.w);
    r[4] = (short)f2bf(hi.x); r[5] = (short)f2bf(hi.y);
    r[6] = (short)f2bf(hi.z); r[7] = (short)f2bf(hi.w);
    return r;
}

// Convert user embeds to the bf16 catH user section.
__global__ __launch_bounds__(256) void cvt_usr_k(
        const float* __restrict__ usr, ushort_t* __restrict__ usrH, long nU) {
    long i = ((long)blockIdx.x * blockDim.x + threadIdx.x) * 8;
    if (i >= nU) return;
    float4 a = *(const float4*)(usr + i);
    float4 b = *(const float4*)(usr + i + 4);
    ushort4 lo; lo.x = f2bf(a.x); lo.y = f2bf(a.y); lo.z = f2bf(a.z); lo.w = f2bf(a.w);
    ushort4 hi; hi.x = f2bf(b.x); hi.y = f2bf(b.y); hi.z = f2bf(b.z); hi.w = f2bf(b.w);
    *(ushort4*)(usrH + i) = lo;
    *(ushort4*)(usrH + i + 4) = hi;
}

// ---------------- CSR build: binned counting sort (zero global atomics) ------

// P1: per-block LDS histogram over coarse bins; write block's bin row.
__global__ __launch_bounds__(256) void p1_hist_k(
        const int* __restrict__ kg_src, const int* __restrict__ iu_dst,
        const int* __restrict__ ui_dst, int* __restrict__ H,
        int E_kg, int E_iu, int E_ui, int n_items, int S1, int SU, int nbins) {
    __shared__ int h[512];
    int tid = threadIdx.x;
    h[tid] = 0; h[tid + 256] = 0;
    __syncthreads();
    long tot = (long)E_kg + E_iu + E_ui;
    long b0 = (long)blockIdx.x * 2048 + tid;
#pragma unroll
    for (int j = 0; j < 8; ++j) {
        long t = b0 + (long)j * 256;
        if (t < tot) {
            int slot;
            if (t < E_kg) slot = kg_src[t];
            else if (t < (long)E_kg + E_iu) slot = S1 + iu_dst[t - E_kg] - n_items;
            else slot = S1 + SU + ui_dst[t - E_kg - E_iu];
            atomicAdd(&h[slot >> BSH], 1);
        }
    }
    __syncthreads();
    int* row = H + (size_t)blockIdx.x * nbins;
    if (tid < nbins) row[tid] = h[tid];
    if (tid + 256 < nbins) row[tid + 256] = h[tid + 256];
}

// P2a: per-bin column scan over blocks (in place) -> binTotal.
__global__ __launch_bounds__(256) void p2a_scan_k(int* __restrict__ H,
        int* __restrict__ binTotal, int NBLK, int nbins) {
    int bin = blockIdx.x, tid = threadIdx.x;
    int lane = tid & 63, w = tid >> 6;
    __shared__ int wtot[4];
    int carry = 0;
    for (int c0 = 0; c0 < NBLK; c0 += 256) {
        int idx = c0 + tid;
        int v = (idx < NBLK) ? H[(size_t)idx * nbins + bin] : 0;
        int inc = v;
#pragma unroll
        for (int off = 1; off < 64; off <<= 1) {
            int u = __shfl_up(inc, off);
            if (lane >= off) inc += u;
        }
        if (lane == 63) wtot[w] = inc;
        __syncthreads();
        int woff = 0;
        for (int i = 0; i < w; ++i) woff += wtot[i];
        int ctot = wtot[0] + wtot[1] + wtot[2] + wtot[3];
        if (idx < NBLK) H[(size_t)idx * nbins + bin] = carry + woff + inc - v;
        carry += ctot;
        __syncthreads();
    }
    if (tid == 0) binTotal[bin] = carry;
}

// P2b: exclusive scan of binTotal -> binStart (nbins <= 512).
__global__ __launch_bounds__(512) void p2b_bins_k(const int* __restrict__ binTotal,
        int* __restrict__ binStart, int nbins) {
    int tid = threadIdx.x, lane = tid & 63, w = tid >> 6;
    __shared__ int wtot[8];
    int v = (tid < nbins) ? binTotal[tid] : 0;
    int inc = v;
#pragma unroll
    for (int off = 1; off < 64; off <<= 1) {
        int u = __shfl_up(inc, off);
        if (lane >= off) inc += u;
    }
    if (lane == 63) wtot[w] = inc;
    __syncthreads();
    int woff = 0;
    for (int i = 0; i < w; ++i) woff += wtot[i];
    if (tid < nbins) binStart[tid] = woff + inc - v;
    if (tid == 0) {
        int tot = 0;
        for (int i = 0; i < 8; ++i) tot += wtot[i];
        binStart[nbins] = tot;
    }
}

// P3: scatter records into bin-grouped order via LDS cursors.
__global__ __launch_bounds__(256) void p3_scat_k(
        const int* __restrict__ kg_src, const int* __restrict__ kg_dst,
        const int* __restrict__ kg_typ, const int* __restrict__ iu_src,
        const int* __restrict__ iu_dst, const int* __restrict__ ui_src,
        const int* __restrict__ ui_dst,
        const int* __restrict__ H, const int* __restrict__ binStart,
        int2* __restrict__ recA,
        int E_kg, int E_iu, int E_ui, int n_items, int S1, int SU, int nbins) {
    __shared__ int off[512];
    int tid = threadIdx.x;
    const int* row = H + (size_t)blockIdx.x * nbins;
    if (tid < nbins) off[tid] = binStart[tid] + row[tid];
    if (tid + 256 < nbins) off[tid + 256] = binStart[tid + 256] + row[tid + 256];
    __syncthreads();
    long tot = (long)E_kg + E_iu + E_ui;
    long b0 = (long)blockIdx.x * 2048 + tid;
#pragma unroll
    for (int j = 0; j < 8; ++j) {
        long t = b0 + (long)j * 256;
        if (t < tot) {
            int slot, aux;
            if (t < E_kg) {
                slot = kg_src[t];
                aux = kg_dst[t] | ((kg_typ[t] + 2) << 18);
            } else if (t < (long)E_kg + E_iu) {
                long e = t - E_kg;
                slot = S1 + iu_dst[e] - n_items;
                aux = iu_src[e];
            } else {
                long e = t - E_kg - E_iu;
                slot = S1 + SU + ui_dst[e];
                aux = ui_src[e];
            }
            int pos = atomicAdd(&off[slot >> BSH], 1);
            recA[pos] = make_int2(slot, aux);
        }
    }
}

// P4: per-bin fine sort: LDS hist over 512 slots -> deg/base + final scatter.
__global__ __launch_bounds__(256) void p4_sort_k(
        const int2* __restrict__ recA, const int* __restrict__ binStart,
        int2* __restrict__ recB, int* __restrict__ deg, int* __restrict__ base,
        int nbins) {
    int b = blockIdx.x, tid = threadIdx.x;
    int lane = tid & 63, w = tid >> 6;
    int lo = binStart[b], cnt = binStart[b + 1] - lo;
    __shared__ int h[512];
    __shared__ int pre[512];
    __shared__ int wtot[4];
    h[tid] = 0; h[tid + 256] = 0;
    __syncthreads();
    for (int i = tid; i < cnt; i += 256)
        atomicAdd(&h[recA[lo + i].x & 511], 1);
    __syncthreads();
    int v1 = h[tid];
    int inc = v1;
#pragma unroll
    for (int off = 1; off < 64; off <<= 1) {
        int u = __shfl_up(inc, off);
        if (lane >= off) inc += u;
    }
    if (lane == 63) wtot[w] = inc;
    __syncthreads();
    int woff = 0;
    for (int i = 0; i < w; ++i) woff += wtot[i];
    int T1 = wtot[0] + wtot[1] + wtot[2] + wtot[3];
    int p1 = woff + inc - v1;
    __syncthreads();
    int v2 = h[tid + 256];
    inc = v2;
#pragma unroll
    for (int off = 1; off < 64; off <<= 1) {
        int u = __shfl_up(inc, off);
        if (lane >= off) inc += u;
    }
    if (lane == 63) wtot[w] = inc;
    __syncthreads();
    woff = 0;
    for (int i = 0; i < w; ++i) woff += wtot[i];
    int p2 = T1 + woff + inc - v2;
    pre[tid] = p1; pre[tid + 256] = p2;
    int slot0 = (b << BSH) + tid;
    deg[slot0] = v1;       base[slot0] = lo + p1;
    deg[slot0 + 256] = v2; base[slot0 + 256] = lo + p2;
    __syncthreads();
    for (int i = tid; i < cnt; i += 256) {
        int2 r = recA[lo + i];
        int p = atomicAdd(&pre[r.x & 511], 1);
        recB[lo + p] = r;
    }
}

// ---------------- KG path ----------------

// Merged dots+chain in CSR (slot) order; 4 lanes/edge coalesced reads,
// 2-step shfl reduce, fast-math chain; payload write coalesced at slot.
__global__ __launch_bounds__(256) void kg_edge_fused_k(const float* __restrict__ ent,
                          const float* __restrict__ rel,
                          const int2* __restrict__ rec,
                          float4* __restrict__ payload,
                          int nE) {
    int w = blockIdx.x * 4 + (threadIdx.x >> 6);
    int l = threadIdx.x & 63;
    int slot = w * 16 + (l >> 2);
    if (slot >= nE) return;
    int j0 = l & 3;
    int2 rc = rec[slot];
    int s = rc.x, d = rc.y & 0x3FFFF, ty = rc.y >> 18;
    const float4* pu = (const float4*)(ent + (size_t)s * 64);
    const float4* pv = (const float4*)(ent + (size_t)d * 64);
    const float4* pr = (const float4*)(rel + (size_t)ty * 64);

    float uu = 0.f, vv = 0.f, rr = 0.f, uv = 0.f, ur = 0.f, vr = 0.f;
#pragma unroll
    for (int i = 0; i < 4; ++i) {
        float4 a = pu[4 * i + j0], b = pv[4 * i + j0], c = pr[4 * i + j0];
        uu += dot4(a, a); vv += dot4(b, b); rr += dot4(c, c);
        uv += dot4(a, b); ur += dot4(a, c); vr += dot4(b, c);
    }
#pragma unroll
    for (int m = 1; m < 4; m <<= 1) {
        uu += __shfl_xor(uu, m);
        vv += __shfl_xor(vv, m);
        rr += __shfl_xor(rr, m);
        uv += __shfl_xor(uv, m);
        ur += __shfl_xor(ur, m);
        vr += __shfl_xor(vr, m);
    }

    float n0 = sqrtf(fmaxf(uu, EPSF));
    float cp = tanh_f(n0) * frcp(n0);
    float p2 = cp * cp * uu;
    float om_p2 = 1.f - p2;
    float lam = 2.f * frcp(fmaxf(om_p2, EPSF));

    float nv = sqrtf(fmaxf(vv, EPSF));
    float cd = tanh_f(0.5f * lam * nv) * frcp(nv);
    float wd2 = cd * cd * vv;
    float pwd = cp * cd * uv;
    float iDd = frcp(fmaxf(1.f + 2.f * pwd + p2 * wd2, EPSF));
    float a1 = (1.f + 2.f * pwd + wd2) * cp * iDd;
    float b1 = om_p2 * cd * iDd;

    float nr = sqrtf(fmaxf(rr, EPSF));
    float cr = tanh_f(0.5f * lam * nr) * frcp(nr);
    float wr2 = cr * cr * rr;
    float pwr = cp * cr * ur;
    float iDr = frcp(fmaxf(1.f + 2.f * pwr + p2 * wr2, EPSF));
    float a2 = (1.f + 2.f * pwr + wr2) * cp * iDr;
    float c2 = om_p2 * cr * iDr;

    float x2 = a1 * a1 * uu + 2.f * a1 * b1 * uv + b1 * b1 * vv;
    float y2 = a2 * a2 * uu + 2.f * a2 * c2 * ur + c2 * c2 * rr;
    float xy = a1 * a2 * uu + a1 * c2 * ur + b1 * a2 * uv + b1 * c2 * vr;
    float iden = frcp(fmaxf(1.f + 2.f * xy + x2 * y2, EPSF));
    float E = (1.f + 2.f * xy + y2) * iden;
    float F = (1.f - x2) * iden;
    float zu = E * a1 + F * a2;
    float zv = E * b1;
    float zr = F * c2;

    float z2 = zu * zu * uu + zv * zv * vv + zr * zr * rr
             + 2.f * (zu * zv * uv + zu * zr * ur + zv * zr * vr);
    float nz = sqrtf(fmaxf(z2, EPSF));
    if (nz > MAXN) {
        float sc = MAXN * frcp(nz);
        zu *= sc; zv *= sc; zr *= sc;
        z2 *= sc * sc;
    }

    float mxy = -cp * (zu * uu + zv * uv + zr * ur);
    float idenl = frcp(fmaxf(1.f + 2.f * mxy + p2 * z2, EPSF));
    float G = (1.f + 2.f * mxy + z2) * idenl;
    float H = om_p2 * idenl;
    float su = -G * cp + H * zu;
    float sv = H * zv;
    float sr = H * zr;

    float ns2 = su * su * uu + sv * sv * vv + sr * sr * rr
              + 2.f * (su * sv * uv + su * sr * ur + sv * sr * vr);
    float ns = sqrtf(fmaxf(ns2, EPSF));
    float k = fmaxf(om_p2, EPSF) * atanh_f(fminf(ns, MAXN)) * frcp(ns);

    if (j0 == 0) {
        payload[slot] = make_float4(k * sv, k * sr, k * su, __int_as_float(rc.y));
    }
}

// Wave-per-entity CSR gather (best measured form), 4x unrolled, f32 reads;
// emits item-row norms and bf16 catH item rows.
__global__ void kg_gather_k(const float* __restrict__ ent,
                            const float* __restrict__ rel,
                            const int* __restrict__ deg,
                            const int* __restrict__ base,
                            const float4* __restrict__ payload,
                            float* __restrict__ out_final,
                            float* __restrict__ out_items,
                            ushort_t* __restrict__ catH,
                            float* __restrict__ normv,
                            int n_items, int n) {
    int i = blockIdx.x * (blockDim.x >> 6) + (threadIdx.x >> 6);
    if (i >= n) return;
    int l = threadIdx.x & 63;
    int b = base[i], dg = deg[i];
    float acc = 0.f, as = 0.f;
    int q = 0;
    for (; q + 4 <= dg; q += 4) {
        float4 p0 = payload[b + q];
        float4 p1 = payload[b + q + 1];
        float4 p2 = payload[b + q + 2];
        float4 p3 = payload[b + q + 3];
        int w0 = __float_as_int(p0.w), w1 = __float_as_int(p1.w);
        int w2 = __float_as_int(p2.w), w3 = __float_as_int(p3.w);
        float v0 = ent[(size_t)(w0 & 0x3FFFF) * 64 + l];
        float r0 = rel[(size_t)(w0 >> 18) * 64 + l];
        float v1 = ent[(size_t)(w1 & 0x3FFFF) * 64 + l];
        float r1 = rel[(size_t)(w1 >> 18) * 64 + l];
        float v2 = ent[(size_t)(w2 & 0x3FFFF) * 64 + l];
        float r2 = rel[(size_t)(w2 >> 18) * 64 + l];
        float v3 = ent[(size_t)(w3 & 0x3FFFF) * 64 + l];
        float r3 = rel[(size_t)(w3 >> 18) * 64 + l];
        acc += p0.x * v0 + p0.y * r0 + p1.x * v1 + p1.y * r1;
        acc += p2.x * v2 + p2.y * r2 + p3.x * v3 + p3.y * r3;
        as += (p0.z + p1.z) + (p2.z + p3.z);
    }
    for (; q < dg; ++q) {
        float4 p = payload[b + q];
        int w = __float_as_int(p.w);
        acc += p.x * ent[(size_t)(w & 0x3FFFF) * 64 + l]
             + p.y * rel[(size_t)(w >> 18) * 64 + l];
        as += p.z;
    }
    float v = (acc + as * ent[(size_t)i * 64 + l]) * frcp(fmaxf((float)dg, 1.f));
    if (i < n_items) {
        out_items[(size_t)i * 64 + l] = v;
        catH[(size_t)i * 64 + l] = f2bf(v);
        float s2 = wsum64(v * v);
        if (l == 0) normv[i] = s2;
    } else {
        out_final[(size_t)i * 64 + l] = v;
    }
}

// norms for the user half of cat_nodes
__global__ void user_norm_k(const float* __restrict__ user, float* __restrict__ normv,
                            int n_items, int n_usr) {
    int j = blockIdx.x * (blockDim.x >> 6) + (threadIdx.x >> 6);
    if (j >= n_usr) return;
    int l = threadIdx.x & 63;
    float c = user[(size_t)j * 64 + l];
    float s = wsum64(c * c);
    if (l == 0) normv[n_items + j] = s;
}

// ---------------- CF path ----------------

// Wave = 2 consecutive users, combined contiguous range, 8-deep unroll,
// unified bf16 cat table (no items/user branch).
__global__ void iu_gather_k(const ushort_t* __restrict__ catH,
                            const int* __restrict__ deg, const int* __restrict__ base,
                            const int2* __restrict__ rec,
                            float* __restrict__ out_u, int n, int SOFF) {
    int w = blockIdx.x * (blockDim.x >> 6) + (threadIdx.x >> 6);
    int i0 = w * 2;
    if (i0 >= n) return;
    bool has1 = (i0 + 1 < n);
    int l = threadIdx.x & 63;
    int b0 = base[SOFF + i0];
    int d0 = deg[SOFF + i0];
    int d1 = has1 ? deg[SOFF + i0 + 1] : 0;
    int cnt = d0 + d1;
    int split = b0 + d0;
    float acc0 = 0.f, acc1 = 0.f;
    int q = 0;
    for (; q + 8 <= cnt; q += 8) {
        float vs[8]; bool s0[8];
#pragma unroll
        for (int j = 0; j < 8; ++j) {
            int sidx = rec[b0 + q + j].y;
            vs[j] = bf2f(catH[(size_t)sidx * 64 + l]);
            s0[j] = (b0 + q + j) < split;
        }
#pragma unroll
        for (int j = 0; j < 8; ++j) {
            acc0 += s0[j] ? vs[j] : 0.f;
            acc1 += s0[j] ? 0.f : vs[j];
        }
    }
    for (; q < cnt; ++q) {
        int sidx = rec[b0 + q].y;
        float v = bf2f(catH[(size_t)sidx * 64 + l]);
        bool s0 = (b0 + q) < split;
        acc0 += s0 ? v : 0.f;
        acc1 += s0 ? 0.f : v;
    }
    out_u[(size_t)i0 * 64 + l] = acc0 * frcp(fmaxf((float)d0, 1.f));
    if (has1)
        out_u[(size_t)(i0 + 1) * 64 + l] = acc1 * frcp(fmaxf((float)d1, 1.f));
}

// Wave = 2 consecutive items, combined range, 8-deep unroll:
// icf[i] = norm[i]*(sum cat[s]/(norm[s]+1e-6))/deg, bf16 cat rows.
__global__ void ui_gather_k(const ushort_t* __restrict__ catH,
                            const float* __restrict__ normv,
                            const int* __restrict__ deg, const int* __restrict__ base,
                            const int2* __restrict__ rec,
                            float* __restrict__ icf, int n, int SOFF) {
    int w = blockIdx.x * (blockDim.x >> 6) + (threadIdx.x >> 6);
    int i0 = w * 2;
    if (i0 >= n) return;
    bool has1 = (i0 + 1 < n);
    int l = threadIdx.x & 63;
    int b0 = base[SOFF + i0];
    int d0 = deg[SOFF + i0];
    int d1 = has1 ? deg[SOFF + i0 + 1] : 0;
    int cnt = d0 + d1;
    int split = b0 + d0;
    float acc0 = 0.f, acc1 = 0.f;
    int q = 0;
    for (; q + 8 <= cnt; q += 8) {
        int ss[8]; float fs[8], vs[8]; bool s0[8];
#pragma unroll
        for (int j = 0; j < 8; ++j) ss[j] = rec[b0 + q + j].y;
#pragma unroll
        for (int j = 0; j < 8; ++j) fs[j] = frcp(normv[ss[j]] + 1e-6f);
#pragma unroll
        for (int j = 0; j < 8; ++j) {
            vs[j] = bf2f(catH[(size_t)ss[j] * 64 + l]);
            s0[j] = (b0 + q + j) < split;
        }
#pragma unroll
        for (int j = 0; j < 8; ++j) {
            float t = fs[j] * vs[j];
            acc0 += s0[j] ? t : 0.f;
            acc1 += s0[j] ? 0.f : t;
        }
    }
    for (; q < cnt; ++q) {
        int sidx = rec[b0 + q].y;
        float t = frcp(normv[sidx] + 1e-6f) * bf2f(catH[(size_t)sidx * 64 + l]);
        bool s0 = (b0 + q) < split;
        acc0 += s0 ? t : 0.f;
        acc1 += s0 ? 0.f : t;
    }
    icf[(size_t)i0 * 64 + l] = normv[i0] * acc0 * frcp(fmaxf((float)d0, 1.f));
    if (has1)
        icf[(size_t)(i0 + 1) * 64 + l] =
            normv[i0 + 1] * acc1 * frcp(fmaxf((float)d1, 1.f));
}

// MFMA gate+fusion: acc = [oi|cf] @ [W1;W2]^T (bf16), out = g*oi + (1-g)*cf.
__global__ __launch_bounds__(256) void fusion_mfma_k(const float* __restrict__ items,
                          const float* __restrict__ icf,
                          const float* __restrict__ W1, const float* __restrict__ W2,
                          float* __restrict__ outf, int n_items) {
    int lane = threadIdx.x & 63;
    int row0 = blockIdx.x * 64 + (threadIdx.x >> 6) * 16;
    int r = lane & 15, g = lane >> 4;

    int arow = row0 + r;
    size_t rbase = (size_t)(arow < n_items ? arow : 0) * 64;

    bf16x8 afrag[4];
#pragma unroll
    for (int s = 0; s < 4; ++s) {
        int kb = s * 32 + g * 8;
        const float* p = (kb < 64) ? (items + rbase + kb) : (icf + rbase + kb - 64);
        afrag[s] = pack8(p);
    }

    bf16x8 bfrag[4][4];
#pragma unroll
    for (int c = 0; c < 4; ++c) {
        int col = c * 16 + r;
#pragma unroll
        for (int s = 0; s < 4; ++s) {
            int kb = s * 32 + g * 8;
            const float* p = (kb < 64) ? (W1 + col * 64 + kb) : (W2 + col * 64 + kb - 64);
            bfrag[c][s] = pack8(p);
        }
    }

    f32x4 acc[4] = {{0.f,0.f,0.f,0.f},{0.f,0.f,0.f,0.f},
                    {0.f,0.f,0.f,0.f},{0.f,0.f,0.f,0.f}};
#pragma unroll
    for (int s = 0; s < 4; ++s)
#pragma unroll
        for (int c = 0; c < 4; ++c)
            acc[c] = __builtin_amdgcn_mfma_f32_16x16x32_bf16(afrag[s], bfrag[c][s],
                                                             acc[c], 0, 0, 0);

#pragma unroll
    for (int c = 0; c < 4; ++c) {
        int col = c * 16 + r;
#pragma unroll
        for (int q = 0; q < 4; ++q) {
            int orow = row0 + g * 4 + q;
            if (orow < n_items) {
                size_t off = (size_t)orow * 64 + col;
                float oi = items[off], cf = icf[off];
                float gate = frcp(1.f + __expf(-acc[c][q]));
                outf[off] = gate * oi + (1.f - gate) * cf;
            }
        }
    }
}

extern "C" void kernel_launch(void* const* d_in, const int* in_sizes, int n_in,
                              void* d_out, int out_size, void* d_ws, size_t ws_size,
                              hipStream_t stream) {
    const float* ent    = (const float*)d_in[0];
    const float* usr    = (const float*)d_in[1];
    const float* rel    = (const float*)d_in[2];
    const float* W1     = (const float*)d_in[3];
    const float* W2     = (const float*)d_in[4];
    const int*   kg_src = (const int*)d_in[5];
    const int*   kg_dst = (const int*)d_in[6];
    const int*   kg_typ = (const int*)d_in[7];
    const int*   iu_src = (const int*)d_in[8];
    const int*   iu_dst = (const int*)d_in[9];
    const int*   ui_src = (const int*)d_in[10];
    const int*   ui_dst = (const int*)d_in[11];

    const int n_ent   = in_sizes[0] / 64;
    const int n_usr   = in_sizes[1] / 64;
    const int E_kg    = in_sizes[5];
    const int E_iu    = in_sizes[8];
    const int E_ui    = in_sizes[10];
    const int n_items = (out_size - in_sizes[0] - in_sizes[1]) / 64;
    const int N       = n_items + n_usr;

    // unified slot space: [ent | user | item], each 512-aligned
    const int S1 = ((n_ent + 511) / 512) * 512;
    const int SU = ((n_usr + 511) / 512) * 512;
    const int SI = ((n_items + 511) / 512) * 512;
    const int S3 = S1 + SU + SI;
    const int nbins = S3 >> BSH;
    const long tot = (long)E_kg + E_iu + E_ui;
    const int NBLK = (int)((tot + 2047) / 2048);

    float* out_final = (float*)d_out;                        // (n_ent,64)
    float* out_u     = out_final + (size_t)n_ent * 64;       // (n_usr,64)
    float* out_items = out_u + (size_t)n_usr * 64;           // (n_items,64)

    // d_out tail scratch (dead before kg/iu gathers write these chunks):
    int2* recA = (int2*)out_u;                               // tot * 8B
    int*  H    = (int*)(recA + tot);                         // NBLK*nbins*4B

    float* ws = (float*)d_ws;
    size_t o = 0;
    int* binTotal = (int*)(ws + o); o += nbins;
    int* binStart = (int*)(ws + o); o += nbins + 1;
    int* deg      = (int*)(ws + o); o += S3;
    int* basep    = (int*)(ws + o); o += S3;
    o = (o + 3) & ~(size_t)3;                      // 16B align
    int2* recB    = (int2*)(ws + o); o += (size_t)tot * 2;
    float4* pay_kg = (float4*)(ws + o); o += (size_t)E_kg * 4;
    float* icf    = (float*)pay_kg;   // alias: pay_kg dead after kg_gather
    float* normv  = ws + o; o += N;
    o = (o + 3) & ~(size_t)3;
    ushort_t* catH = (ushort_t*)(ws + o); o += (size_t)N * 32;
    ushort_t* usrH = catH + (size_t)n_items * 64;  // user section of catH

    // bf16 user table (runs first; no deps on sort)
    long nU64 = (long)n_usr * 64;
    cvt_usr_k<<<(int)((nU64 / 8 + 255) / 256), 256, 0, stream>>>(usr, usrH, nU64);

    // CSR build (all LDS atomics; no memsets - every buffer fully written)
    p1_hist_k<<<NBLK, 256, 0, stream>>>(kg_src, iu_dst, ui_dst, H,
                                        E_kg, E_iu, E_ui, n_items, S1, SU, nbins);
    p2a_scan_k<<<nbins, 256, 0, stream>>>(H, binTotal, NBLK, nbins);
    p2b_bins_k<<<1, 512, 0, stream>>>(binTotal, binStart, nbins);
    p3_scat_k<<<NBLK, 256, 0, stream>>>(kg_src, kg_dst, kg_typ, iu_src, iu_dst,
                                        ui_src, ui_dst, H, binStart, recA,
                                        E_kg, E_iu, E_ui, n_items, S1, SU, nbins);
    p4_sort_k<<<nbins, 256, 0, stream>>>(recA, binStart, recB, deg, basep, nbins);

    // KG compute (CSR-ordered edge pass; kg records = recB[0..E_kg))
    kg_edge_fused_k<<<(E_kg + 63) / 64, 256, 0, stream>>>(ent, rel, recB,
                                                          pay_kg, E_kg);
    kg_gather_k<<<(n_ent + 3) / 4, 256, 0, stream>>>(ent, rel, deg, basep, pay_kg,
                                                     out_final, out_items, catH,
                                                     normv, n_items, n_ent);
    user_norm_k<<<(n_usr + 3) / 4, 256, 0, stream>>>(usr, normv, n_items, n_usr);

    // CF gathers (direct output writes; recA/H in d_out are dead by now)
    int wv_u = (n_usr + 1) / 2;
    iu_gather_k<<<(wv_u + 3) / 4, 256, 0, stream>>>(catH, deg, basep, recB,
                                                    out_u, n_usr, S1);
    int wv_i = (n_items + 1) / 2;
    ui_gather_k<<<(wv_i + 3) / 4, 256, 0, stream>>>(catH, normv, deg, basep, recB,
                                                    icf, n_items, S1 + SU);
    fusion_mfma_k<<<(n_items + 63) / 64, 256, 0, stream>>>(out_items, icf, W1, W2,
                                                           out_final, n_items);
}